// Round 4
// baseline (1418.028 us; speedup 1.0000x reference)
//
#include <hip/hip_runtime.h>

// Problem constants (fixed by reference)
#define NN   50000
#define NNP  50048   // padded to 391*128
#define NE   800000
#define DIN  512
#define DH   512
#define DE   256

typedef __bf16 bf16_t;
typedef __bf16 bf16x4 __attribute__((ext_vector_type(4)));
typedef __bf16 bf16x8 __attribute__((ext_vector_type(8)));
typedef float  f32x4  __attribute__((ext_vector_type(4)));

// ---------------- utility kernels ----------------

__global__ void k_zero_i32(int* p, int n) {
    int i = blockIdx.x * blockDim.x + threadIdx.x;
    if (i < n) p[i] = 0;
}

__global__ void k_indeg(const int* __restrict__ dst, int* __restrict__ indeg, int e) {
    int i = blockIdx.x * blockDim.x + threadIdx.x;
    if (i < e) atomicAdd(&indeg[dst[i]], 1);
}

// Single-block exclusive scan over indeg -> rowptr, cursor; dis = rsqrt(indeg+1)
__global__ __launch_bounds__(1024) void k_scan(const int* __restrict__ indeg,
                                               int* __restrict__ rowptr,
                                               int* __restrict__ cursor,
                                               float* __restrict__ dis, int n) {
    __shared__ int s[1024];
    __shared__ int carry_s;
    if (threadIdx.x == 0) carry_s = 0;
    __syncthreads();
    for (int base = 0; base < n; base += 1024) {
        int i = base + (int)threadIdx.x;
        int v = (i < n) ? indeg[i] : 0;
        s[threadIdx.x] = v;
        __syncthreads();
        #pragma unroll
        for (int off = 1; off < 1024; off <<= 1) {
            int t = (threadIdx.x >= (unsigned)off) ? s[threadIdx.x - off] : 0;
            __syncthreads();
            s[threadIdx.x] += t;
            __syncthreads();
        }
        int incl = s[threadIdx.x];
        int excl = incl - v;
        int carry = carry_s;
        if (i < n) {
            int start = carry + excl;
            rowptr[i] = start;
            cursor[i] = start;
            dis[i] = rsqrtf((float)(v + 1));
            if (i == n - 1) rowptr[n] = carry + incl;
        }
        __syncthreads();
        if (threadIdx.x == 1023) carry_s = carry + incl;
        __syncthreads();
    }
}

__global__ void k_fill(const int* __restrict__ src, const int* __restrict__ dst,
                       int* __restrict__ cursor, int* __restrict__ csr, int e) {
    int i = blockIdx.x * blockDim.x + threadIdx.x;
    if (i < e) {
        int d = dst[i];
        int p = atomicAdd(&cursor[d], 1);
        csr[p] = src[i];
    }
}

// ---------------- split helpers ----------------

// X [M,K] fp32 -> Ah/Al [Mpad,K] bf16 (hi/lo split), zero-padding rows >= M.
__global__ void k_split_pad(const float* __restrict__ X, bf16_t* __restrict__ Ah,
                            bf16_t* __restrict__ Al, int M, int K, long total4) {
    long idx = (long)blockIdx.x * blockDim.x + threadIdx.x;
    if (idx >= total4) return;
    long base = idx * 4;
    int row = (int)(base / K);
    f32x4 v;
    if (row < M) v = *(const f32x4*)(X + base);
    else { v[0] = 0.f; v[1] = 0.f; v[2] = 0.f; v[3] = 0.f; }
    bf16x4 h, l;
    #pragma unroll
    for (int c = 0; c < 4; ++c) {
        float f = v[c];
        bf16_t hh = (bf16_t)f;
        h[c] = hh;
        l[c] = (bf16_t)(f - (float)hh);
    }
    *(bf16x4*)(Ah + base) = h;
    *(bf16x4*)(Al + base) = l;
}

// W [K,N] fp32 -> Bth/Btl [N,K] bf16 (transpose + hi/lo split). Tiny matrices.
__global__ void k_splitT(const float* __restrict__ W, bf16_t* __restrict__ Bth,
                         bf16_t* __restrict__ Btl, int K, int N) {
    int idx = blockIdx.x * blockDim.x + threadIdx.x;
    if (idx >= K * N) return;
    int k = idx / N, n = idx % N;
    float f = W[idx];
    bf16_t h = (bf16_t)f;
    Bth[(size_t)n * K + k] = h;
    Btl[(size_t)n * K + k] = (bf16_t)(f - (float)h);
}

// ---------------- MFMA split-bf16 GEMM ----------------
// C[M,N] (fp32) = A[M,K] @ B[K,N] where A = Ah+Al, Bt = Bh+Bl stored [N,K] bf16.
// 128x128 tile, BK=32, 256 threads (4 waves, each 64x64 as 4x4 of 16x16x32 MFMA).

__device__ __forceinline__ void gld_lds16(const void* g, void* l) {
    __builtin_amdgcn_global_load_lds(
        (const __attribute__((address_space(1))) unsigned int*)g,
        (__attribute__((address_space(3))) unsigned int*)l, 16, 0, 0);
}

__global__ __launch_bounds__(256) void k_gemm_split(
    const bf16_t* __restrict__ Ah, const bf16_t* __restrict__ Al,
    const bf16_t* __restrict__ Bh, const bf16_t* __restrict__ Bl,  // [N,K]
    float* __restrict__ C, int M, int N, int K) {
    __shared__ alignas(16) bf16_t sAh[128 * 32];
    __shared__ alignas(16) bf16_t sAl[128 * 32];
    __shared__ alignas(16) bf16_t sBh[128 * 32];
    __shared__ alignas(16) bf16_t sBl[128 * 32];

    const int tid = threadIdx.x;
    const int wave = tid >> 6, lane = tid & 63;
    const int quad = lane >> 4, l16 = lane & 15;
    const int bm = blockIdx.y * 128, bn = blockIdx.x * 128;
    const int wm = (wave & 1) * 64, wn = (wave >> 1) * 64;

    f32x4 acc[4][4];
    #pragma unroll
    for (int i = 0; i < 4; ++i)
        #pragma unroll
        for (int j = 0; j < 4; ++j)
            #pragma unroll
            for (int r = 0; r < 4; ++r) acc[i][j][r] = 0.f;

    // staging: each wave stages 32 rows (2 chunks of 16) of each 128x32 tile
    const int srow = wave * 32 + (lane >> 2);      // global row offset within tile
    const int sseg = (lane & 3) * 16;              // byte segment within 64B row
    char* lds0A = (char*)sAh + wave * 32 * 64;     // wave-uniform LDS bases
    char* lds0a = (char*)sAl + wave * 32 * 64;
    char* lds0B = (char*)sBh + wave * 32 * 64;
    char* lds0b = (char*)sBl + wave * 32 * 64;

    const char* gAh0 = (const char*)(Ah + (size_t)(bm + srow) * K) + sseg;
    const char* gAl0 = (const char*)(Al + (size_t)(bm + srow) * K) + sseg;
    const char* gBh0 = (const char*)(Bh + (size_t)(bn + srow) * K) + sseg;
    const char* gBl0 = (const char*)(Bl + (size_t)(bn + srow) * K) + sseg;
    const size_t rstep = (size_t)16 * K * 2;       // 16 rows in bytes

    for (int k0 = 0; k0 < K; k0 += 32) {
        const size_t kb = (size_t)k0 * 2;
        gld_lds16(gAh0 + kb,         lds0A);
        gld_lds16(gAh0 + kb + rstep, lds0A + 1024);
        gld_lds16(gAl0 + kb,         lds0a);
        gld_lds16(gAl0 + kb + rstep, lds0a + 1024);
        gld_lds16(gBh0 + kb,         lds0B);
        gld_lds16(gBh0 + kb + rstep, lds0B + 1024);
        gld_lds16(gBl0 + kb,         lds0b);
        gld_lds16(gBl0 + kb + rstep, lds0b + 1024);
        __syncthreads();

        bf16x8 fah[4], fal[4], fbh[4], fbl[4];
        #pragma unroll
        for (int i = 0; i < 4; ++i) {
            fah[i] = *(const bf16x8*)(sAh + (wm + 16 * i + l16) * 32 + quad * 8);
            fal[i] = *(const bf16x8*)(sAl + (wm + 16 * i + l16) * 32 + quad * 8);
            fbh[i] = *(const bf16x8*)(sBh + (wn + 16 * i + l16) * 32 + quad * 8);
            fbl[i] = *(const bf16x8*)(sBl + (wn + 16 * i + l16) * 32 + quad * 8);
        }
        #pragma unroll
        for (int i = 0; i < 4; ++i)
            #pragma unroll
            for (int j = 0; j < 4; ++j) {
                acc[i][j] = __builtin_amdgcn_mfma_f32_16x16x32_bf16(fah[i], fbh[j], acc[i][j], 0, 0, 0);
                acc[i][j] = __builtin_amdgcn_mfma_f32_16x16x32_bf16(fah[i], fbl[j], acc[i][j], 0, 0, 0);
                acc[i][j] = __builtin_amdgcn_mfma_f32_16x16x32_bf16(fal[i], fbh[j], acc[i][j], 0, 0, 0);
            }
        __syncthreads();
    }

    #pragma unroll
    for (int i = 0; i < 4; ++i) {
        #pragma unroll
        for (int j = 0; j < 4; ++j) {
            int col = bn + wn + 16 * j + l16;
            #pragma unroll
            for (int r = 0; r < 4; ++r) {
                int row = bm + wm + 16 * i + quad * 4 + r;
                if (row < M) C[(size_t)row * N + col] = acc[i][j][r];
            }
        }
    }
}

// ---------------- aggregation ----------------
// out[i] = (sum_{e:dst=i} t[src]*dis[src] + t[i]*dis[i])*dis[i] + b
// Rotating-register software pipeline: batch i+1's loads issue before batch i's
// FMAs, keeping 4 x 1KB row-loads in flight per wave (memory-level parallelism).

// Layers 1-2: fused relu + bf16 hi/lo split output (feeds next GEMM). D=512.
__global__ __launch_bounds__(128) void k_agg_split(
    const float* __restrict__ t, const int* __restrict__ rowptr,
    const int* __restrict__ csr, const float* __restrict__ dis,
    const float* __restrict__ bias,
    bf16_t* __restrict__ Ah, bf16_t* __restrict__ Al) {
    const int node = blockIdx.x;
    const int tid = threadIdx.x;  // 128 threads
    const int beg = rowptr[node], end = rowptr[node + 1];
    const float din = dis[node];
    const int en = end - 1;

    f32x4 a0, a1, a2, a3;
    #pragma unroll
    for (int c = 0; c < 4; ++c) { a0[c] = 0.f; a1[c] = 0.f; a2[c] = 0.f; a3[c] = 0.f; }

    f32x4 nv0, nv1, nv2, nv3;
    float nw0, nw1, nw2, nw3;

    // prologue: issue batch 0
    {
        int e = beg;
        int i0 = e,     i1 = (e + 1 <= en) ? e + 1 : en;
        int i2 = (e + 2 <= en) ? e + 2 : en, i3 = (e + 3 <= en) ? e + 3 : en;
        int s0 = csr[i0], s1 = csr[i1], s2 = csr[i2], s3 = csr[i3];
        nw0 = dis[s0];
        nw1 = (e + 1 <= en) ? dis[s1] : 0.f;
        nw2 = (e + 2 <= en) ? dis[s2] : 0.f;
        nw3 = (e + 3 <= en) ? dis[s3] : 0.f;
        nv0 = ((const f32x4*)(t + (size_t)s0 * DH))[tid];
        nv1 = ((const f32x4*)(t + (size_t)s1 * DH))[tid];
        nv2 = ((const f32x4*)(t + (size_t)s2 * DH))[tid];
        nv3 = ((const f32x4*)(t + (size_t)s3 * DH))[tid];
    }

    for (int e = beg; e < end; ) {
        // rotate: wait on batch i, move to cur
        f32x4 v0 = nv0, v1 = nv1, v2 = nv2, v3 = nv3;
        float w0 = nw0, w1 = nw1, w2 = nw2, w3 = nw3;
        e += 4;
        if (e < end) {
            // issue batch i+1 (stays in flight during batch i's FMAs)
            int i0 = e,     i1 = (e + 1 <= en) ? e + 1 : en;
            int i2 = (e + 2 <= en) ? e + 2 : en, i3 = (e + 3 <= en) ? e + 3 : en;
            int s0 = csr[i0], s1 = csr[i1], s2 = csr[i2], s3 = csr[i3];
            nw0 = dis[s0];
            nw1 = (e + 1 <= en) ? dis[s1] : 0.f;
            nw2 = (e + 2 <= en) ? dis[s2] : 0.f;
            nw3 = (e + 3 <= en) ? dis[s3] : 0.f;
            nv0 = ((const f32x4*)(t + (size_t)s0 * DH))[tid];
            nv1 = ((const f32x4*)(t + (size_t)s1 * DH))[tid];
            nv2 = ((const f32x4*)(t + (size_t)s2 * DH))[tid];
            nv3 = ((const f32x4*)(t + (size_t)s3 * DH))[tid];
        }
        #pragma unroll
        for (int c = 0; c < 4; ++c) {
            a0[c] = fmaf(v0[c], w0, a0[c]);
            a1[c] = fmaf(v1[c], w1, a1[c]);
            a2[c] = fmaf(v2[c], w2, a2[c]);
            a3[c] = fmaf(v3[c], w3, a3[c]);
        }
    }

    f32x4 sv = ((const f32x4*)(t + (size_t)node * DH))[tid];
    f32x4 bv = ((const f32x4*)bias)[tid];
    bf16x4 h, l;
    #pragma unroll
    for (int c = 0; c < 4; ++c) {
        float acc = (a0[c] + a1[c]) + (a2[c] + a3[c]);
        float o = fmaf(fmaf(sv[c], din, acc), din, bv[c]);
        o = fmaxf(o, 0.f);
        bf16_t hh = (bf16_t)o;
        h[c] = hh;
        l[c] = (bf16_t)(o - (float)hh);
    }
    *(bf16x4*)(Ah + (size_t)node * DH + tid * 4) = h;
    *(bf16x4*)(Al + (size_t)node * DH + tid * 4) = l;
}

// Layer 3: fp32 output (emb), no relu. D=256.
__global__ __launch_bounds__(64) void k_agg_f32(
    const float* __restrict__ t, const int* __restrict__ rowptr,
    const int* __restrict__ csr, const float* __restrict__ dis,
    const float* __restrict__ bias, float* __restrict__ out) {
    const int node = blockIdx.x;
    const int tid = threadIdx.x;  // 64 threads
    const int beg = rowptr[node], end = rowptr[node + 1];
    const float din = dis[node];
    const int en = end - 1;

    f32x4 a0, a1, a2, a3;
    #pragma unroll
    for (int c = 0; c < 4; ++c) { a0[c] = 0.f; a1[c] = 0.f; a2[c] = 0.f; a3[c] = 0.f; }

    f32x4 nv0, nv1, nv2, nv3;
    float nw0, nw1, nw2, nw3;
    {
        int e = beg;
        int i0 = e,     i1 = (e + 1 <= en) ? e + 1 : en;
        int i2 = (e + 2 <= en) ? e + 2 : en, i3 = (e + 3 <= en) ? e + 3 : en;
        int s0 = csr[i0], s1 = csr[i1], s2 = csr[i2], s3 = csr[i3];
        nw0 = dis[s0];
        nw1 = (e + 1 <= en) ? dis[s1] : 0.f;
        nw2 = (e + 2 <= en) ? dis[s2] : 0.f;
        nw3 = (e + 3 <= en) ? dis[s3] : 0.f;
        nv0 = ((const f32x4*)(t + (size_t)s0 * DE))[tid];
        nv1 = ((const f32x4*)(t + (size_t)s1 * DE))[tid];
        nv2 = ((const f32x4*)(t + (size_t)s2 * DE))[tid];
        nv3 = ((const f32x4*)(t + (size_t)s3 * DE))[tid];
    }

    for (int e = beg; e < end; ) {
        f32x4 v0 = nv0, v1 = nv1, v2 = nv2, v3 = nv3;
        float w0 = nw0, w1 = nw1, w2 = nw2, w3 = nw3;
        e += 4;
        if (e < end) {
            int i0 = e,     i1 = (e + 1 <= en) ? e + 1 : en;
            int i2 = (e + 2 <= en) ? e + 2 : en, i3 = (e + 3 <= en) ? e + 3 : en;
            int s0 = csr[i0], s1 = csr[i1], s2 = csr[i2], s3 = csr[i3];
            nw0 = dis[s0];
            nw1 = (e + 1 <= en) ? dis[s1] : 0.f;
            nw2 = (e + 2 <= en) ? dis[s2] : 0.f;
            nw3 = (e + 3 <= en) ? dis[s3] : 0.f;
            nv0 = ((const f32x4*)(t + (size_t)s0 * DE))[tid];
            nv1 = ((const f32x4*)(t + (size_t)s1 * DE))[tid];
            nv2 = ((const f32x4*)(t + (size_t)s2 * DE))[tid];
            nv3 = ((const f32x4*)(t + (size_t)s3 * DE))[tid];
        }
        #pragma unroll
        for (int c = 0; c < 4; ++c) {
            a0[c] = fmaf(v0[c], w0, a0[c]);
            a1[c] = fmaf(v1[c], w1, a1[c]);
            a2[c] = fmaf(v2[c], w2, a2[c]);
            a3[c] = fmaf(v3[c], w3, a3[c]);
        }
    }

    f32x4 sv = ((const f32x4*)(t + (size_t)node * DE))[tid];
    f32x4 bv = ((const f32x4*)bias)[tid];
    f32x4 o;
    #pragma unroll
    for (int c = 0; c < 4; ++c) {
        float acc = (a0[c] + a1[c]) + (a2[c] + a3[c]);
        o[c] = fmaf(fmaf(sv[c], din, acc), din, bv[c]);
    }
    ((f32x4*)(out + (size_t)node * DE))[tid] = o;
}

// ---------------- heads: emb[n,256] @ {We[256,7], Wh[256,8], Wg[256,57]} ----------------

__global__ __launch_bounds__(256) void k_heads(const float* __restrict__ emb,
    const float* __restrict__ We, const float* __restrict__ be,
    const float* __restrict__ Wh, const float* __restrict__ bh,
    const float* __restrict__ Wg, const float* __restrict__ bg,
    float* __restrict__ oe, float* __restrict__ oh, float* __restrict__ og, int n) {
    __shared__ float Ws[128 * 72];
    __shared__ float bs[72];
    const int tid = threadIdx.x;
    if (tid < 72) bs[tid] = (tid < 7) ? be[tid] : (tid < 15 ? bh[tid - 7] : bg[tid - 15]);
    const int row0 = blockIdx.x * 24;
    const int c = tid % 72;
    const int rr = tid / 72;  // 0..3, rr==3 lanes idle for compute
    float acc[8];
    #pragma unroll
    for (int i = 0; i < 8; ++i) acc[i] = 0.f;

    for (int chunk = 0; chunk < 2; ++chunk) {
        __syncthreads();
        for (int idx = tid; idx < 128 * 72; idx += 256) {
            int k = idx / 72 + chunk * 128;
            int cc = idx % 72;
            float w;
            if (cc < 7) w = We[k * 7 + cc];
            else if (cc < 15) w = Wh[k * 8 + (cc - 7)];
            else w = Wg[k * 57 + (cc - 15)];
            Ws[idx] = w;
        }
        __syncthreads();
        if (rr < 3) {
            #pragma unroll
            for (int ri = 0; ri < 8; ++ri) {
                int r = row0 + rr + ri * 3;
                if (r < n) {
                    const float* a = emb + (size_t)r * 256 + chunk * 128;
                    float s = acc[ri];
                    #pragma unroll 8
                    for (int k = 0; k < 128; k += 4) {
                        float4 av = *(const float4*)(a + k);
                        s = fmaf(av.x, Ws[(k + 0) * 72 + c], s);
                        s = fmaf(av.y, Ws[(k + 1) * 72 + c], s);
                        s = fmaf(av.z, Ws[(k + 2) * 72 + c], s);
                        s = fmaf(av.w, Ws[(k + 3) * 72 + c], s);
                    }
                    acc[ri] = s;
                }
            }
        }
    }
    if (rr < 3) {
        #pragma unroll
        for (int ri = 0; ri < 8; ++ri) {
            int r = row0 + rr + ri * 3;
            if (r < n) {
                float v = acc[ri] + bs[c];
                if (c < 7) oe[(size_t)r * 7 + c] = v;
                else if (c < 15) oh[(size_t)r * 8 + (c - 7)] = v;
                else og[(size_t)r * 57 + (c - 15)] = v;
            }
        }
    }
}

// ---------------- launch ----------------

extern "C" void kernel_launch(void* const* d_in, const int* in_sizes, int n_in,
                              void* d_out, int out_size, void* d_ws, size_t ws_size,
                              hipStream_t stream) {
    const float* x   = (const float*)d_in[0];
    const int*   ei  = (const int*)d_in[1];
    const float* W1  = (const float*)d_in[2];
    const float* b1  = (const float*)d_in[3];
    const float* W2  = (const float*)d_in[4];
    const float* b2  = (const float*)d_in[5];
    const float* W3  = (const float*)d_in[6];
    const float* b3  = (const float*)d_in[7];
    const float* We  = (const float*)d_in[8];
    const float* be  = (const float*)d_in[9];
    const float* Wh  = (const float*)d_in[10];
    const float* bh  = (const float*)d_in[11];
    const float* Wg  = (const float*)d_in[12];
    const float* bg  = (const float*)d_in[13];

    const int* e_src = ei;
    const int* e_dst = ei + NE;

    // workspace layout (~210 MB)
    float*  bufA = (float*)d_ws;                       // 50000*512 fp32 (GEMM out)
    bf16_t* Ah   = (bf16_t*)(bufA + (size_t)NN * DH);  // 50048*512 bf16
    bf16_t* Al   = Ah + (size_t)NNP * DH;
    bf16_t* Bth  = Al + (size_t)NNP * DH;              // 512*512 bf16
    bf16_t* Btl  = Bth + (size_t)DH * DH;
    int*   indeg  = (int*)(Btl + (size_t)DH * DH);
    int*   rowptr = indeg + 50048;                     // 50001 used
    int*   cursor = rowptr + 50048;
    float* dis    = (float*)(cursor + 50048);
    int*   csr    = (int*)(dis + 50048);               // 800000

    float* emb   = (float*)d_out;                       // 50000*256
    float* out_e = emb + (size_t)NN * DE;               // 50000*7
    float* out_h = out_e + (size_t)NN * 7;              // 50000*8
    float* out_g = out_h + (size_t)NN * 8;              // 50000*57

    // 1) CSR build
    k_zero_i32<<<(NN + 255) / 256, 256, 0, stream>>>(indeg, NN);
    k_indeg<<<(NE + 255) / 256, 256, 0, stream>>>(e_dst, indeg, NE);
    k_scan<<<1, 1024, 0, stream>>>(indeg, rowptr, cursor, dis, NN);
    k_fill<<<(NE + 255) / 256, 256, 0, stream>>>(e_src, e_dst, cursor, csr, NE);

    const int gy = NNP / 128;  // 391
    const long total4 = (long)NNP * DH / 4;

    // 2) layer 1
    k_split_pad<<<(int)((total4 + 255) / 256), 256, 0, stream>>>(x, Ah, Al, NN, DIN, total4);
    k_splitT<<<(DH * DH + 255) / 256, 256, 0, stream>>>(W1, Bth, Btl, DIN, DH);
    k_gemm_split<<<dim3(DH / 128, gy), 256, 0, stream>>>(Ah, Al, Bth, Btl, bufA, NN, DH, DIN);
    k_agg_split<<<NN, 128, 0, stream>>>(bufA, rowptr, csr, dis, b1, Ah, Al);

    // 3) layer 2
    k_splitT<<<(DH * DH + 255) / 256, 256, 0, stream>>>(W2, Bth, Btl, DH, DH);
    k_gemm_split<<<dim3(DH / 128, gy), 256, 0, stream>>>(Ah, Al, Bth, Btl, bufA, NN, DH, DH);
    k_agg_split<<<NN, 128, 0, stream>>>(bufA, rowptr, csr, dis, b2, Ah, Al);

    // 4) layer 3 -> emb (no relu)
    k_splitT<<<(DH * DE + 255) / 256, 256, 0, stream>>>(W3, Bth, Btl, DH, DE);
    k_gemm_split<<<dim3(DE / 128, gy), 256, 0, stream>>>(Ah, Al, Bth, Btl, bufA, NN, DE, DH);
    k_agg_f32<<<NN, 64, 0, stream>>>(bufA, rowptr, csr, dis, b3, emb);

    // 5) heads
    k_heads<<<(NN + 23) / 24, 256, 0, stream>>>(emb, We, be, Wh, bh, Wg, bg,
                                                out_e, out_h, out_g, NN);
}

// Round 5
// 1109.560 us; speedup vs baseline: 1.2780x; 1.2780x over previous
//
#include <hip/hip_runtime.h>

// Problem constants (fixed by reference)
#define NN   50000
#define NNP  50048   // padded to 391*128
#define NE   800000
#define DIN  512
#define DH   512
#define DE   256

typedef __bf16 bf16_t;
typedef __bf16 bf16x4 __attribute__((ext_vector_type(4)));
typedef __bf16 bf16x8 __attribute__((ext_vector_type(8)));
typedef float  f32x4  __attribute__((ext_vector_type(4)));
typedef _Float16 half_t;
typedef _Float16 half4 __attribute__((ext_vector_type(4)));
typedef _Float16 half8 __attribute__((ext_vector_type(8)));

// ---------------- utility kernels ----------------

__global__ void k_zero_i32(int* p, int n) {
    int i = blockIdx.x * blockDim.x + threadIdx.x;
    if (i < n) p[i] = 0;
}

__global__ void k_indeg(const int* __restrict__ dst, int* __restrict__ indeg, int e) {
    int i = blockIdx.x * blockDim.x + threadIdx.x;
    if (i < e) atomicAdd(&indeg[dst[i]], 1);
}

// Single-block exclusive scan over indeg -> rowptr, cursor; dis = rsqrt(indeg+1)
__global__ __launch_bounds__(1024) void k_scan(const int* __restrict__ indeg,
                                               int* __restrict__ rowptr,
                                               int* __restrict__ cursor,
                                               float* __restrict__ dis, int n) {
    __shared__ int s[1024];
    __shared__ int carry_s;
    if (threadIdx.x == 0) carry_s = 0;
    __syncthreads();
    for (int base = 0; base < n; base += 1024) {
        int i = base + (int)threadIdx.x;
        int v = (i < n) ? indeg[i] : 0;
        s[threadIdx.x] = v;
        __syncthreads();
        #pragma unroll
        for (int off = 1; off < 1024; off <<= 1) {
            int t = (threadIdx.x >= (unsigned)off) ? s[threadIdx.x - off] : 0;
            __syncthreads();
            s[threadIdx.x] += t;
            __syncthreads();
        }
        int incl = s[threadIdx.x];
        int excl = incl - v;
        int carry = carry_s;
        if (i < n) {
            int start = carry + excl;
            rowptr[i] = start;
            cursor[i] = start;
            dis[i] = rsqrtf((float)(v + 1));
            if (i == n - 1) rowptr[n] = carry + incl;
        }
        __syncthreads();
        if (threadIdx.x == 1023) carry_s = carry + incl;
        __syncthreads();
    }
}

__global__ void k_fill(const int* __restrict__ src, const int* __restrict__ dst,
                       int* __restrict__ cursor, int* __restrict__ csr, int e) {
    int i = blockIdx.x * blockDim.x + threadIdx.x;
    if (i < e) {
        int d = dst[i];
        int p = atomicAdd(&cursor[d], 1);
        csr[p] = src[i];
    }
}

// ---------------- split helpers ----------------

// X [M,K] fp32 -> Ah/Al [Mpad,K] bf16 (hi/lo split), zero-padding rows >= M.
__global__ void k_split_pad(const float* __restrict__ X, bf16_t* __restrict__ Ah,
                            bf16_t* __restrict__ Al, int M, int K, long total4) {
    long idx = (long)blockIdx.x * blockDim.x + threadIdx.x;
    if (idx >= total4) return;
    long base = idx * 4;
    int row = (int)(base / K);
    f32x4 v;
    if (row < M) v = *(const f32x4*)(X + base);
    else { v[0] = 0.f; v[1] = 0.f; v[2] = 0.f; v[3] = 0.f; }
    bf16x4 h, l;
    #pragma unroll
    for (int c = 0; c < 4; ++c) {
        float f = v[c];
        bf16_t hh = (bf16_t)f;
        h[c] = hh;
        l[c] = (bf16_t)(f - (float)hh);
    }
    *(bf16x4*)(Ah + base) = h;
    *(bf16x4*)(Al + base) = l;
}

// W [K,N] fp32 -> Bth/Btl [N,K] bf16 (transpose + hi/lo split). Tiny matrices.
__global__ void k_splitT(const float* __restrict__ W, bf16_t* __restrict__ Bth,
                         bf16_t* __restrict__ Btl, int K, int N) {
    int idx = blockIdx.x * blockDim.x + threadIdx.x;
    if (idx >= K * N) return;
    int k = idx / N, n = idx % N;
    float f = W[idx];
    bf16_t h = (bf16_t)f;
    Bth[(size_t)n * K + k] = h;
    Btl[(size_t)n * K + k] = (bf16_t)(f - (float)h);
}

// ---------------- MFMA split-bf16 GEMM ----------------
// C[M,N] (fp16) = A[M,K] @ B[K,N] where A = Ah+Al, Bt = Bh+Bl stored [N,K] bf16.
// 128x128 tile, BK=32, 256 threads (4 waves, each 64x64 as 4x4 of 16x16x32 MFMA).
// C is written fp16: halves agg-gather traffic; quantization ~2^-11 relative.

__device__ __forceinline__ void gld_lds16(const void* g, void* l) {
    __builtin_amdgcn_global_load_lds(
        (const __attribute__((address_space(1))) unsigned int*)g,
        (__attribute__((address_space(3))) unsigned int*)l, 16, 0, 0);
}

__global__ __launch_bounds__(256) void k_gemm_split(
    const bf16_t* __restrict__ Ah, const bf16_t* __restrict__ Al,
    const bf16_t* __restrict__ Bh, const bf16_t* __restrict__ Bl,  // [N,K]
    half_t* __restrict__ C, int M, int N, int K) {
    __shared__ alignas(16) bf16_t sAh[128 * 32];
    __shared__ alignas(16) bf16_t sAl[128 * 32];
    __shared__ alignas(16) bf16_t sBh[128 * 32];
    __shared__ alignas(16) bf16_t sBl[128 * 32];

    const int tid = threadIdx.x;
    const int wave = tid >> 6, lane = tid & 63;
    const int quad = lane >> 4, l16 = lane & 15;
    const int bm = blockIdx.y * 128, bn = blockIdx.x * 128;
    const int wm = (wave & 1) * 64, wn = (wave >> 1) * 64;

    f32x4 acc[4][4];
    #pragma unroll
    for (int i = 0; i < 4; ++i)
        #pragma unroll
        for (int j = 0; j < 4; ++j)
            #pragma unroll
            for (int r = 0; r < 4; ++r) acc[i][j][r] = 0.f;

    // staging: each wave stages 32 rows (2 chunks of 16) of each 128x32 tile
    const int srow = wave * 32 + (lane >> 2);      // global row offset within tile
    const int sseg = (lane & 3) * 16;              // byte segment within 64B row
    char* lds0A = (char*)sAh + wave * 32 * 64;     // wave-uniform LDS bases
    char* lds0a = (char*)sAl + wave * 32 * 64;
    char* lds0B = (char*)sBh + wave * 32 * 64;
    char* lds0b = (char*)sBl + wave * 32 * 64;

    const char* gAh0 = (const char*)(Ah + (size_t)(bm + srow) * K) + sseg;
    const char* gAl0 = (const char*)(Al + (size_t)(bm + srow) * K) + sseg;
    const char* gBh0 = (const char*)(Bh + (size_t)(bn + srow) * K) + sseg;
    const char* gBl0 = (const char*)(Bl + (size_t)(bn + srow) * K) + sseg;
    const size_t rstep = (size_t)16 * K * 2;       // 16 rows in bytes

    for (int k0 = 0; k0 < K; k0 += 32) {
        const size_t kb = (size_t)k0 * 2;
        gld_lds16(gAh0 + kb,         lds0A);
        gld_lds16(gAh0 + kb + rstep, lds0A + 1024);
        gld_lds16(gAl0 + kb,         lds0a);
        gld_lds16(gAl0 + kb + rstep, lds0a + 1024);
        gld_lds16(gBh0 + kb,         lds0B);
        gld_lds16(gBh0 + kb + rstep, lds0B + 1024);
        gld_lds16(gBl0 + kb,         lds0b);
        gld_lds16(gBl0 + kb + rstep, lds0b + 1024);
        __syncthreads();

        bf16x8 fah[4], fal[4], fbh[4], fbl[4];
        #pragma unroll
        for (int i = 0; i < 4; ++i) {
            fah[i] = *(const bf16x8*)(sAh + (wm + 16 * i + l16) * 32 + quad * 8);
            fal[i] = *(const bf16x8*)(sAl + (wm + 16 * i + l16) * 32 + quad * 8);
            fbh[i] = *(const bf16x8*)(sBh + (wn + 16 * i + l16) * 32 + quad * 8);
            fbl[i] = *(const bf16x8*)(sBl + (wn + 16 * i + l16) * 32 + quad * 8);
        }
        #pragma unroll
        for (int i = 0; i < 4; ++i)
            #pragma unroll
            for (int j = 0; j < 4; ++j) {
                acc[i][j] = __builtin_amdgcn_mfma_f32_16x16x32_bf16(fah[i], fbh[j], acc[i][j], 0, 0, 0);
                acc[i][j] = __builtin_amdgcn_mfma_f32_16x16x32_bf16(fah[i], fbl[j], acc[i][j], 0, 0, 0);
                acc[i][j] = __builtin_amdgcn_mfma_f32_16x16x32_bf16(fal[i], fbh[j], acc[i][j], 0, 0, 0);
            }
        __syncthreads();
    }

    #pragma unroll
    for (int i = 0; i < 4; ++i) {
        #pragma unroll
        for (int j = 0; j < 4; ++j) {
            int col = bn + wn + 16 * j + l16;
            #pragma unroll
            for (int r = 0; r < 4; ++r) {
                int row = bm + wm + 16 * i + quad * 4 + r;
                if (row < M) C[(size_t)row * N + col] = (half_t)acc[i][j][r];
            }
        }
    }
}

// ---------------- aggregation ----------------
// out[i] = (sum_{e:dst=i} t[src]*dis[src] + t[i]*dis[i])*dis[i] + b
// t is fp16 (halved gather bytes). Rotating 4-deep pipeline for MLP.

// Layers 1-2: fused relu + bf16 hi/lo split output. D=512. 2 nodes / 128-thread block.
__global__ __launch_bounds__(128) void k_agg_split(
    const half_t* __restrict__ t, const int* __restrict__ rowptr,
    const int* __restrict__ csr, const float* __restrict__ dis,
    const float* __restrict__ bias,
    bf16_t* __restrict__ Ah, bf16_t* __restrict__ Al) {
    const int node = blockIdx.x * 2 + (threadIdx.x >> 6);
    const int lane = threadIdx.x & 63;  // 64 lanes x 8 elems (16B loads)
    const int beg = rowptr[node], end = rowptr[node + 1];
    const float din = dis[node];
    const int en = end - 1;

    float a0[8], a1[8], a2[8], a3[8];
    #pragma unroll
    for (int c = 0; c < 8; ++c) { a0[c] = 0.f; a1[c] = 0.f; a2[c] = 0.f; a3[c] = 0.f; }

    if (beg < end) {
        half8 nv0, nv1, nv2, nv3;
        float nw0, nw1, nw2, nw3;
        {
            int e = beg;
            int i1 = (e + 1 <= en) ? e + 1 : en;
            int i2 = (e + 2 <= en) ? e + 2 : en;
            int i3 = (e + 3 <= en) ? e + 3 : en;
            int s0 = csr[e], s1 = csr[i1], s2 = csr[i2], s3 = csr[i3];
            nw0 = dis[s0];
            nw1 = (e + 1 <= en) ? dis[s1] : 0.f;
            nw2 = (e + 2 <= en) ? dis[s2] : 0.f;
            nw3 = (e + 3 <= en) ? dis[s3] : 0.f;
            nv0 = ((const half8*)(t + (size_t)s0 * DH))[lane];
            nv1 = ((const half8*)(t + (size_t)s1 * DH))[lane];
            nv2 = ((const half8*)(t + (size_t)s2 * DH))[lane];
            nv3 = ((const half8*)(t + (size_t)s3 * DH))[lane];
        }
        for (int e = beg; e < end; ) {
            half8 v0 = nv0, v1 = nv1, v2 = nv2, v3 = nv3;
            float w0 = nw0, w1 = nw1, w2 = nw2, w3 = nw3;
            e += 4;
            if (e < end) {
                int i1 = (e + 1 <= en) ? e + 1 : en;
                int i2 = (e + 2 <= en) ? e + 2 : en;
                int i3 = (e + 3 <= en) ? e + 3 : en;
                int s0 = csr[e], s1 = csr[i1], s2 = csr[i2], s3 = csr[i3];
                nw0 = dis[s0];
                nw1 = (e + 1 <= en) ? dis[s1] : 0.f;
                nw2 = (e + 2 <= en) ? dis[s2] : 0.f;
                nw3 = (e + 3 <= en) ? dis[s3] : 0.f;
                nv0 = ((const half8*)(t + (size_t)s0 * DH))[lane];
                nv1 = ((const half8*)(t + (size_t)s1 * DH))[lane];
                nv2 = ((const half8*)(t + (size_t)s2 * DH))[lane];
                nv3 = ((const half8*)(t + (size_t)s3 * DH))[lane];
            }
            #pragma unroll
            for (int c = 0; c < 8; ++c) {
                a0[c] = fmaf((float)v0[c], w0, a0[c]);
                a1[c] = fmaf((float)v1[c], w1, a1[c]);
                a2[c] = fmaf((float)v2[c], w2, a2[c]);
                a3[c] = fmaf((float)v3[c], w3, a3[c]);
            }
        }
    }

    half8 sv = ((const half8*)(t + (size_t)node * DH))[lane];
    f32x4 bv0 = ((const f32x4*)bias)[lane * 2];
    f32x4 bv1 = ((const f32x4*)bias)[lane * 2 + 1];
    bf16x8 h, l;
    #pragma unroll
    for (int c = 0; c < 8; ++c) {
        float b = (c < 4) ? bv0[c] : bv1[c - 4];
        float acc = (a0[c] + a1[c]) + (a2[c] + a3[c]);
        float o = fmaf(fmaf((float)sv[c], din, acc), din, b);
        o = fmaxf(o, 0.f);
        bf16_t hh = (bf16_t)o;
        h[c] = hh;
        l[c] = (bf16_t)(o - (float)hh);
    }
    *(bf16x8*)(Ah + (size_t)node * DH + lane * 8) = h;
    *(bf16x8*)(Al + (size_t)node * DH + lane * 8) = l;
}

// Layer 3: fp32 output (emb), no relu. D=256. 4 nodes / 128-thread block.
__global__ __launch_bounds__(128) void k_agg_f32(
    const half_t* __restrict__ t, const int* __restrict__ rowptr,
    const int* __restrict__ csr, const float* __restrict__ dis,
    const float* __restrict__ bias, float* __restrict__ out) {
    const int node = blockIdx.x * 4 + (threadIdx.x >> 5);
    const int lane = threadIdx.x & 31;  // 32 lanes x 8 elems (16B loads)
    const int beg = rowptr[node], end = rowptr[node + 1];
    const float din = dis[node];
    const int en = end - 1;

    float a0[8], a1[8], a2[8], a3[8];
    #pragma unroll
    for (int c = 0; c < 8; ++c) { a0[c] = 0.f; a1[c] = 0.f; a2[c] = 0.f; a3[c] = 0.f; }

    if (beg < end) {
        half8 nv0, nv1, nv2, nv3;
        float nw0, nw1, nw2, nw3;
        {
            int e = beg;
            int i1 = (e + 1 <= en) ? e + 1 : en;
            int i2 = (e + 2 <= en) ? e + 2 : en;
            int i3 = (e + 3 <= en) ? e + 3 : en;
            int s0 = csr[e], s1 = csr[i1], s2 = csr[i2], s3 = csr[i3];
            nw0 = dis[s0];
            nw1 = (e + 1 <= en) ? dis[s1] : 0.f;
            nw2 = (e + 2 <= en) ? dis[s2] : 0.f;
            nw3 = (e + 3 <= en) ? dis[s3] : 0.f;
            nv0 = ((const half8*)(t + (size_t)s0 * DE))[lane];
            nv1 = ((const half8*)(t + (size_t)s1 * DE))[lane];
            nv2 = ((const half8*)(t + (size_t)s2 * DE))[lane];
            nv3 = ((const half8*)(t + (size_t)s3 * DE))[lane];
        }
        for (int e = beg; e < end; ) {
            half8 v0 = nv0, v1 = nv1, v2 = nv2, v3 = nv3;
            float w0 = nw0, w1 = nw1, w2 = nw2, w3 = nw3;
            e += 4;
            if (e < end) {
                int i1 = (e + 1 <= en) ? e + 1 : en;
                int i2 = (e + 2 <= en) ? e + 2 : en;
                int i3 = (e + 3 <= en) ? e + 3 : en;
                int s0 = csr[e], s1 = csr[i1], s2 = csr[i2], s3 = csr[i3];
                nw0 = dis[s0];
                nw1 = (e + 1 <= en) ? dis[s1] : 0.f;
                nw2 = (e + 2 <= en) ? dis[s2] : 0.f;
                nw3 = (e + 3 <= en) ? dis[s3] : 0.f;
                nv0 = ((const half8*)(t + (size_t)s0 * DE))[lane];
                nv1 = ((const half8*)(t + (size_t)s1 * DE))[lane];
                nv2 = ((const half8*)(t + (size_t)s2 * DE))[lane];
                nv3 = ((const half8*)(t + (size_t)s3 * DE))[lane];
            }
            #pragma unroll
            for (int c = 0; c < 8; ++c) {
                a0[c] = fmaf((float)v0[c], w0, a0[c]);
                a1[c] = fmaf((float)v1[c], w1, a1[c]);
                a2[c] = fmaf((float)v2[c], w2, a2[c]);
                a3[c] = fmaf((float)v3[c], w3, a3[c]);
            }
        }
    }

    half8 sv = ((const half8*)(t + (size_t)node * DE))[lane];
    f32x4 bv0 = ((const f32x4*)bias)[lane * 2];
    f32x4 bv1 = ((const f32x4*)bias)[lane * 2 + 1];
    f32x4 o0, o1;
    #pragma unroll
    for (int c = 0; c < 8; ++c) {
        float b = (c < 4) ? bv0[c] : bv1[c - 4];
        float acc = (a0[c] + a1[c]) + (a2[c] + a3[c]);
        float o = fmaf(fmaf((float)sv[c], din, acc), din, b);
        if (c < 4) o0[c] = o; else o1[c - 4] = o;
    }
    ((f32x4*)(out + (size_t)node * DE))[lane * 2]     = o0;
    ((f32x4*)(out + (size_t)node * DE))[lane * 2 + 1] = o1;
}

// ---------------- heads: emb[n,256] @ {We[256,7], Wh[256,8], Wg[256,57]} ----------------

__global__ __launch_bounds__(256) void k_heads(const float* __restrict__ emb,
    const float* __restrict__ We, const float* __restrict__ be,
    const float* __restrict__ Wh, const float* __restrict__ bh,
    const float* __restrict__ Wg, const float* __restrict__ bg,
    float* __restrict__ oe, float* __restrict__ oh, float* __restrict__ og, int n) {
    __shared__ float Ws[128 * 72];
    __shared__ float bs[72];
    const int tid = threadIdx.x;
    if (tid < 72) bs[tid] = (tid < 7) ? be[tid] : (tid < 15 ? bh[tid - 7] : bg[tid - 15]);
    const int row0 = blockIdx.x * 24;
    const int c = tid % 72;
    const int rr = tid / 72;  // 0..3, rr==3 lanes idle for compute
    float acc[8];
    #pragma unroll
    for (int i = 0; i < 8; ++i) acc[i] = 0.f;

    for (int chunk = 0; chunk < 2; ++chunk) {
        __syncthreads();
        for (int idx = tid; idx < 128 * 72; idx += 256) {
            int k = idx / 72 + chunk * 128;
            int cc = idx % 72;
            float w;
            if (cc < 7) w = We[k * 7 + cc];
            else if (cc < 15) w = Wh[k * 8 + (cc - 7)];
            else w = Wg[k * 57 + (cc - 15)];
            Ws[idx] = w;
        }
        __syncthreads();
        if (rr < 3) {
            #pragma unroll
            for (int ri = 0; ri < 8; ++ri) {
                int r = row0 + rr + ri * 3;
                if (r < n) {
                    const float* a = emb + (size_t)r * 256 + chunk * 128;
                    float s = acc[ri];
                    #pragma unroll 8
                    for (int k = 0; k < 128; k += 4) {
                        float4 av = *(const float4*)(a + k);
                        s = fmaf(av.x, Ws[(k + 0) * 72 + c], s);
                        s = fmaf(av.y, Ws[(k + 1) * 72 + c], s);
                        s = fmaf(av.z, Ws[(k + 2) * 72 + c], s);
                        s = fmaf(av.w, Ws[(k + 3) * 72 + c], s);
                    }
                    acc[ri] = s;
                }
            }
        }
    }
    if (rr < 3) {
        #pragma unroll
        for (int ri = 0; ri < 8; ++ri) {
            int r = row0 + rr + ri * 3;
            if (r < n) {
                float v = acc[ri] + bs[c];
                if (c < 7) oe[(size_t)r * 7 + c] = v;
                else if (c < 15) oh[(size_t)r * 8 + (c - 7)] = v;
                else og[(size_t)r * 57 + (c - 15)] = v;
            }
        }
    }
}

// ---------------- launch ----------------

extern "C" void kernel_launch(void* const* d_in, const int* in_sizes, int n_in,
                              void* d_out, int out_size, void* d_ws, size_t ws_size,
                              hipStream_t stream) {
    const float* x   = (const float*)d_in[0];
    const int*   ei  = (const int*)d_in[1];
    const float* W1  = (const float*)d_in[2];
    const float* b1  = (const float*)d_in[3];
    const float* W2  = (const float*)d_in[4];
    const float* b2  = (const float*)d_in[5];
    const float* W3  = (const float*)d_in[6];
    const float* b3  = (const float*)d_in[7];
    const float* We  = (const float*)d_in[8];
    const float* be  = (const float*)d_in[9];
    const float* Wh  = (const float*)d_in[10];
    const float* bh  = (const float*)d_in[11];
    const float* Wg  = (const float*)d_in[12];
    const float* bg  = (const float*)d_in[13];

    const int* e_src = ei;
    const int* e_dst = ei + NE;

    // workspace layout (~160 MB)
    half_t* bufA = (half_t*)d_ws;                       // 50048*512 fp16 (GEMM out)
    bf16_t* Ah   = (bf16_t*)(bufA + (size_t)NNP * DH);  // 50048*512 bf16
    bf16_t* Al   = Ah + (size_t)NNP * DH;
    bf16_t* Bth  = Al + (size_t)NNP * DH;               // 512*512 bf16
    bf16_t* Btl  = Bth + (size_t)DH * DH;
    int*   indeg  = (int*)(Btl + (size_t)DH * DH);
    int*   rowptr = indeg + 50048;                      // 50001 used
    int*   cursor = rowptr + 50048;
    float* dis    = (float*)(cursor + 50048);
    int*   csr    = (int*)(dis + 50048);                // 800000

    float* emb   = (float*)d_out;                       // 50000*256
    float* out_e = emb + (size_t)NN * DE;               // 50000*7
    float* out_h = out_e + (size_t)NN * 7;              // 50000*8
    float* out_g = out_h + (size_t)NN * 8;              // 50000*57

    // 1) CSR build
    k_zero_i32<<<(NN + 255) / 256, 256, 0, stream>>>(indeg, NN);
    k_indeg<<<(NE + 255) / 256, 256, 0, stream>>>(e_dst, indeg, NE);
    k_scan<<<1, 1024, 0, stream>>>(indeg, rowptr, cursor, dis, NN);
    k_fill<<<(NE + 255) / 256, 256, 0, stream>>>(e_src, e_dst, cursor, csr, NE);

    const int gy = NNP / 128;  // 391
    const long total4 = (long)NNP * DH / 4;

    // 2) layer 1
    k_split_pad<<<(int)((total4 + 255) / 256), 256, 0, stream>>>(x, Ah, Al, NN, DIN, total4);
    k_splitT<<<(DH * DH + 255) / 256, 256, 0, stream>>>(W1, Bth, Btl, DIN, DH);
    k_gemm_split<<<dim3(DH / 128, gy), 256, 0, stream>>>(Ah, Al, Bth, Btl, bufA, NN, DH, DIN);
    k_agg_split<<<NN / 2, 128, 0, stream>>>(bufA, rowptr, csr, dis, b1, Ah, Al);

    // 3) layer 2
    k_splitT<<<(DH * DH + 255) / 256, 256, 0, stream>>>(W2, Bth, Btl, DH, DH);
    k_gemm_split<<<dim3(DH / 128, gy), 256, 0, stream>>>(Ah, Al, Bth, Btl, bufA, NN, DH, DH);
    k_agg_split<<<NN / 2, 128, 0, stream>>>(bufA, rowptr, csr, dis, b2, Ah, Al);

    // 4) layer 3 -> emb (no relu)
    k_splitT<<<(DH * DE + 255) / 256, 256, 0, stream>>>(W3, Bth, Btl, DH, DE);
    k_gemm_split<<<dim3(DE / 128, gy), 256, 0, stream>>>(Ah, Al, Bth, Btl, bufA, NN, DE, DH);
    k_agg_f32<<<NN / 4, 128, 0, stream>>>(bufA, rowptr, csr, dis, b3, emb);

    // 5) heads
    k_heads<<<(NN + 23) / 24, 256, 0, stream>>>(emb, We, be, Wh, bh, Wg, bg,
                                                out_e, out_h, out_g, NN);
}

// Round 6
// 1011.956 us; speedup vs baseline: 1.4013x; 1.0965x over previous
//
#include <hip/hip_runtime.h>

// Problem constants (fixed by reference)
#define NN   50000
#define NNP  50048   // padded to 391*128
#define NE   800000
#define DIN  512
#define DH   512
#define DE   256

typedef __bf16 bf16_t;
typedef __bf16 bf16x4 __attribute__((ext_vector_type(4)));
typedef __bf16 bf16x8 __attribute__((ext_vector_type(8)));
typedef float  f32x4  __attribute__((ext_vector_type(4)));
typedef _Float16 half_t;
typedef _Float16 half8 __attribute__((ext_vector_type(8)));

// ---------------- utility kernels ----------------

__global__ void k_zero_i32(int* p, int n) {
    int i = blockIdx.x * blockDim.x + threadIdx.x;
    if (i < n) p[i] = 0;
}

__global__ void k_indeg(const int* __restrict__ dst, int* __restrict__ indeg, int e) {
    int i = blockIdx.x * blockDim.x + threadIdx.x;
    if (i < e) atomicAdd(&indeg[dst[i]], 1);
}

// Single-block exclusive scan over indeg -> rowptr, cursor; dis = rsqrt(indeg+1)
__global__ __launch_bounds__(1024) void k_scan(const int* __restrict__ indeg,
                                               int* __restrict__ rowptr,
                                               int* __restrict__ cursor,
                                               float* __restrict__ dis, int n) {
    __shared__ int s[1024];
    __shared__ int carry_s;
    if (threadIdx.x == 0) carry_s = 0;
    __syncthreads();
    for (int base = 0; base < n; base += 1024) {
        int i = base + (int)threadIdx.x;
        int v = (i < n) ? indeg[i] : 0;
        s[threadIdx.x] = v;
        __syncthreads();
        #pragma unroll
        for (int off = 1; off < 1024; off <<= 1) {
            int t = (threadIdx.x >= (unsigned)off) ? s[threadIdx.x - off] : 0;
            __syncthreads();
            s[threadIdx.x] += t;
            __syncthreads();
        }
        int incl = s[threadIdx.x];
        int excl = incl - v;
        int carry = carry_s;
        if (i < n) {
            int start = carry + excl;
            rowptr[i] = start;
            cursor[i] = start;
            dis[i] = rsqrtf((float)(v + 1));
            if (i == n - 1) rowptr[n] = carry + incl;
        }
        __syncthreads();
        if (threadIdx.x == 1023) carry_s = carry + incl;
        __syncthreads();
    }
}

__global__ void k_fill(const int* __restrict__ src, const int* __restrict__ dst,
                       int* __restrict__ cursor, int* __restrict__ csr, int e) {
    int i = blockIdx.x * blockDim.x + threadIdx.x;
    if (i < e) {
        int d = dst[i];
        int p = atomicAdd(&cursor[d], 1);
        csr[p] = src[i];
    }
}

// ---------------- split helpers ----------------

// X [M,K] fp32 -> Ah/Al [Mpad,K] bf16 (hi/lo split), zero-padding rows >= M.
__global__ void k_split_pad(const float* __restrict__ X, bf16_t* __restrict__ Ah,
                            bf16_t* __restrict__ Al, int M, int K, long total4) {
    long idx = (long)blockIdx.x * blockDim.x + threadIdx.x;
    if (idx >= total4) return;
    long base = idx * 4;
    int row = (int)(base / K);
    f32x4 v;
    if (row < M) v = *(const f32x4*)(X + base);
    else { v[0] = 0.f; v[1] = 0.f; v[2] = 0.f; v[3] = 0.f; }
    bf16x4 h, l;
    #pragma unroll
    for (int c = 0; c < 4; ++c) {
        float f = v[c];
        bf16_t hh = (bf16_t)f;
        h[c] = hh;
        l[c] = (bf16_t)(f - (float)hh);
    }
    *(bf16x4*)(Ah + base) = h;
    *(bf16x4*)(Al + base) = l;
}

// W [K,N] fp32 -> Bth/Btl [N,K] bf16 (transpose + hi/lo split). Tiny matrices.
__global__ void k_splitT(const float* __restrict__ W, bf16_t* __restrict__ Bth,
                         bf16_t* __restrict__ Btl, int K, int N) {
    int idx = blockIdx.x * blockDim.x + threadIdx.x;
    if (idx >= K * N) return;
    int k = idx / N, n = idx % N;
    float f = W[idx];
    bf16_t h = (bf16_t)f;
    Bth[(size_t)n * K + k] = h;
    Btl[(size_t)n * K + k] = (bf16_t)(f - (float)h);
}

// Combined head weights: Wth/Wtl [80][256] bf16 (zero-padded cols 72..79) + bias bc[80].
__global__ void k_headw(const float* __restrict__ We, const float* __restrict__ be,
                        const float* __restrict__ Wh, const float* __restrict__ bh,
                        const float* __restrict__ Wg, const float* __restrict__ bg,
                        bf16_t* __restrict__ Wth, bf16_t* __restrict__ Wtl,
                        float* __restrict__ bc) {
    int idx = blockIdx.x * blockDim.x + threadIdx.x;
    if (idx >= 80 * 256) return;
    int n = idx / 256, k = idx % 256;
    float f = 0.f;
    if (n < 7)       f = We[k * 7 + n];
    else if (n < 15) f = Wh[k * 8 + (n - 7)];
    else if (n < 72) f = Wg[k * 57 + (n - 15)];
    bf16_t h = (bf16_t)f;
    Wth[idx] = h;
    Wtl[idx] = (bf16_t)(f - (float)h);
    if (k == 0) {
        float b = 0.f;
        if (n < 7)       b = be[n];
        else if (n < 15) b = bh[n - 7];
        else if (n < 72) b = bg[n - 15];
        bc[n] = b;
    }
}

// ---------------- MFMA split-bf16 GEMM ----------------
// C[M,N] (fp16) = A[M,K] @ B[K,N] where A = Ah+Al, Bt = Bh+Bl stored [N,K] bf16.
// 128x128 tile, BK=32, 256 threads (4 waves, each 64x64 as 4x4 of 16x16x32 MFMA).

__device__ __forceinline__ void gld_lds16(const void* g, void* l) {
    __builtin_amdgcn_global_load_lds(
        (const __attribute__((address_space(1))) unsigned int*)g,
        (__attribute__((address_space(3))) unsigned int*)l, 16, 0, 0);
}

__global__ __launch_bounds__(256) void k_gemm_split(
    const bf16_t* __restrict__ Ah, const bf16_t* __restrict__ Al,
    const bf16_t* __restrict__ Bh, const bf16_t* __restrict__ Bl,  // [N,K]
    half_t* __restrict__ C, int M, int N, int K) {
    __shared__ alignas(16) bf16_t sAh[128 * 32];
    __shared__ alignas(16) bf16_t sAl[128 * 32];
    __shared__ alignas(16) bf16_t sBh[128 * 32];
    __shared__ alignas(16) bf16_t sBl[128 * 32];

    const int tid = threadIdx.x;
    const int wave = tid >> 6, lane = tid & 63;
    const int quad = lane >> 4, l16 = lane & 15;
    const int bm = blockIdx.y * 128, bn = blockIdx.x * 128;
    const int wm = (wave & 1) * 64, wn = (wave >> 1) * 64;

    f32x4 acc[4][4];
    #pragma unroll
    for (int i = 0; i < 4; ++i)
        #pragma unroll
        for (int j = 0; j < 4; ++j)
            #pragma unroll
            for (int r = 0; r < 4; ++r) acc[i][j][r] = 0.f;

    // staging: each wave stages 32 rows (2 chunks of 16) of each 128x32 tile
    const int srow = wave * 32 + (lane >> 2);      // global row offset within tile
    const int sseg = (lane & 3) * 16;              // byte segment within 64B row
    char* lds0A = (char*)sAh + wave * 32 * 64;     // wave-uniform LDS bases
    char* lds0a = (char*)sAl + wave * 32 * 64;
    char* lds0B = (char*)sBh + wave * 32 * 64;
    char* lds0b = (char*)sBl + wave * 32 * 64;

    const char* gAh0 = (const char*)(Ah + (size_t)(bm + srow) * K) + sseg;
    const char* gAl0 = (const char*)(Al + (size_t)(bm + srow) * K) + sseg;
    const char* gBh0 = (const char*)(Bh + (size_t)(bn + srow) * K) + sseg;
    const char* gBl0 = (const char*)(Bl + (size_t)(bn + srow) * K) + sseg;
    const size_t rstep = (size_t)16 * K * 2;       // 16 rows in bytes

    for (int k0 = 0; k0 < K; k0 += 32) {
        const size_t kb = (size_t)k0 * 2;
        gld_lds16(gAh0 + kb,         lds0A);
        gld_lds16(gAh0 + kb + rstep, lds0A + 1024);
        gld_lds16(gAl0 + kb,         lds0a);
        gld_lds16(gAl0 + kb + rstep, lds0a + 1024);
        gld_lds16(gBh0 + kb,         lds0B);
        gld_lds16(gBh0 + kb + rstep, lds0B + 1024);
        gld_lds16(gBl0 + kb,         lds0b);
        gld_lds16(gBl0 + kb + rstep, lds0b + 1024);
        __syncthreads();

        bf16x8 fah[4], fal[4], fbh[4], fbl[4];
        #pragma unroll
        for (int i = 0; i < 4; ++i) {
            fah[i] = *(const bf16x8*)(sAh + (wm + 16 * i + l16) * 32 + quad * 8);
            fal[i] = *(const bf16x8*)(sAl + (wm + 16 * i + l16) * 32 + quad * 8);
            fbh[i] = *(const bf16x8*)(sBh + (wn + 16 * i + l16) * 32 + quad * 8);
            fbl[i] = *(const bf16x8*)(sBl + (wn + 16 * i + l16) * 32 + quad * 8);
        }
        #pragma unroll
        for (int i = 0; i < 4; ++i)
            #pragma unroll
            for (int j = 0; j < 4; ++j) {
                acc[i][j] = __builtin_amdgcn_mfma_f32_16x16x32_bf16(fah[i], fbh[j], acc[i][j], 0, 0, 0);
                acc[i][j] = __builtin_amdgcn_mfma_f32_16x16x32_bf16(fah[i], fbl[j], acc[i][j], 0, 0, 0);
                acc[i][j] = __builtin_amdgcn_mfma_f32_16x16x32_bf16(fal[i], fbh[j], acc[i][j], 0, 0, 0);
            }
        __syncthreads();
    }

    #pragma unroll
    for (int i = 0; i < 4; ++i) {
        #pragma unroll
        for (int j = 0; j < 4; ++j) {
            int col = bn + wn + 16 * j + l16;
            #pragma unroll
            for (int r = 0; r < 4; ++r) {
                int row = bm + wm + 16 * i + quad * 4 + r;
                if (row < M) C[(size_t)row * N + col] = (half_t)acc[i][j][r];
            }
        }
    }
}

// ---------------- aggregation ----------------
// out[i] = (sum_{e:dst=i} t[src]*dis[src] + t[i]*dis[i])*dis[i] + b
// t is fp16 (halved gather bytes). Rotating 4-deep pipeline for MLP.

// Layers 1-2: fused relu + bf16 hi/lo split output. D=512. 2 nodes / 128-thread block.
__global__ __launch_bounds__(128) void k_agg_split(
    const half_t* __restrict__ t, const int* __restrict__ rowptr,
    const int* __restrict__ csr, const float* __restrict__ dis,
    const float* __restrict__ bias,
    bf16_t* __restrict__ Ah, bf16_t* __restrict__ Al) {
    const int node = blockIdx.x * 2 + (threadIdx.x >> 6);
    const int lane = threadIdx.x & 63;  // 64 lanes x 8 elems (16B loads)
    const int beg = rowptr[node], end = rowptr[node + 1];
    const float din = dis[node];
    const int en = end - 1;

    float a0[8], a1[8], a2[8], a3[8];
    #pragma unroll
    for (int c = 0; c < 8; ++c) { a0[c] = 0.f; a1[c] = 0.f; a2[c] = 0.f; a3[c] = 0.f; }

    if (beg < end) {
        half8 nv0, nv1, nv2, nv3;
        float nw0, nw1, nw2, nw3;
        {
            int e = beg;
            int i1 = (e + 1 <= en) ? e + 1 : en;
            int i2 = (e + 2 <= en) ? e + 2 : en;
            int i3 = (e + 3 <= en) ? e + 3 : en;
            int s0 = csr[e], s1 = csr[i1], s2 = csr[i2], s3 = csr[i3];
            nw0 = dis[s0];
            nw1 = (e + 1 <= en) ? dis[s1] : 0.f;
            nw2 = (e + 2 <= en) ? dis[s2] : 0.f;
            nw3 = (e + 3 <= en) ? dis[s3] : 0.f;
            nv0 = ((const half8*)(t + (size_t)s0 * DH))[lane];
            nv1 = ((const half8*)(t + (size_t)s1 * DH))[lane];
            nv2 = ((const half8*)(t + (size_t)s2 * DH))[lane];
            nv3 = ((const half8*)(t + (size_t)s3 * DH))[lane];
        }
        for (int e = beg; e < end; ) {
            half8 v0 = nv0, v1 = nv1, v2 = nv2, v3 = nv3;
            float w0 = nw0, w1 = nw1, w2 = nw2, w3 = nw3;
            e += 4;
            if (e < end) {
                int i1 = (e + 1 <= en) ? e + 1 : en;
                int i2 = (e + 2 <= en) ? e + 2 : en;
                int i3 = (e + 3 <= en) ? e + 3 : en;
                int s0 = csr[e], s1 = csr[i1], s2 = csr[i2], s3 = csr[i3];
                nw0 = dis[s0];
                nw1 = (e + 1 <= en) ? dis[s1] : 0.f;
                nw2 = (e + 2 <= en) ? dis[s2] : 0.f;
                nw3 = (e + 3 <= en) ? dis[s3] : 0.f;
                nv0 = ((const half8*)(t + (size_t)s0 * DH))[lane];
                nv1 = ((const half8*)(t + (size_t)s1 * DH))[lane];
                nv2 = ((const half8*)(t + (size_t)s2 * DH))[lane];
                nv3 = ((const half8*)(t + (size_t)s3 * DH))[lane];
            }
            #pragma unroll
            for (int c = 0; c < 8; ++c) {
                a0[c] = fmaf((float)v0[c], w0, a0[c]);
                a1[c] = fmaf((float)v1[c], w1, a1[c]);
                a2[c] = fmaf((float)v2[c], w2, a2[c]);
                a3[c] = fmaf((float)v3[c], w3, a3[c]);
            }
        }
    }

    half8 sv = ((const half8*)(t + (size_t)node * DH))[lane];
    f32x4 bv0 = ((const f32x4*)bias)[lane * 2];
    f32x4 bv1 = ((const f32x4*)bias)[lane * 2 + 1];
    bf16x8 h, l;
    #pragma unroll
    for (int c = 0; c < 8; ++c) {
        float b = (c < 4) ? bv0[c] : bv1[c - 4];
        float acc = (a0[c] + a1[c]) + (a2[c] + a3[c]);
        float o = fmaf(fmaf((float)sv[c], din, acc), din, b);
        o = fmaxf(o, 0.f);
        bf16_t hh = (bf16_t)o;
        h[c] = hh;
        l[c] = (bf16_t)(o - (float)hh);
    }
    *(bf16x8*)(Ah + (size_t)node * DH + lane * 8) = h;
    *(bf16x8*)(Al + (size_t)node * DH + lane * 8) = l;
}

// Layer 3: fp32 emb + bf16 hi/lo split (feeds MFMA heads), no relu. D=256.
// 4 nodes / 128-thread block.
__global__ __launch_bounds__(128) void k_agg_f32(
    const half_t* __restrict__ t, const int* __restrict__ rowptr,
    const int* __restrict__ csr, const float* __restrict__ dis,
    const float* __restrict__ bias, float* __restrict__ out,
    bf16_t* __restrict__ Eh, bf16_t* __restrict__ El) {
    const int node = blockIdx.x * 4 + (threadIdx.x >> 5);
    const int lane = threadIdx.x & 31;  // 32 lanes x 8 elems (16B loads)
    const int beg = rowptr[node], end = rowptr[node + 1];
    const float din = dis[node];
    const int en = end - 1;

    float a0[8], a1[8], a2[8], a3[8];
    #pragma unroll
    for (int c = 0; c < 8; ++c) { a0[c] = 0.f; a1[c] = 0.f; a2[c] = 0.f; a3[c] = 0.f; }

    if (beg < end) {
        half8 nv0, nv1, nv2, nv3;
        float nw0, nw1, nw2, nw3;
        {
            int e = beg;
            int i1 = (e + 1 <= en) ? e + 1 : en;
            int i2 = (e + 2 <= en) ? e + 2 : en;
            int i3 = (e + 3 <= en) ? e + 3 : en;
            int s0 = csr[e], s1 = csr[i1], s2 = csr[i2], s3 = csr[i3];
            nw0 = dis[s0];
            nw1 = (e + 1 <= en) ? dis[s1] : 0.f;
            nw2 = (e + 2 <= en) ? dis[s2] : 0.f;
            nw3 = (e + 3 <= en) ? dis[s3] : 0.f;
            nv0 = ((const half8*)(t + (size_t)s0 * DE))[lane];
            nv1 = ((const half8*)(t + (size_t)s1 * DE))[lane];
            nv2 = ((const half8*)(t + (size_t)s2 * DE))[lane];
            nv3 = ((const half8*)(t + (size_t)s3 * DE))[lane];
        }
        for (int e = beg; e < end; ) {
            half8 v0 = nv0, v1 = nv1, v2 = nv2, v3 = nv3;
            float w0 = nw0, w1 = nw1, w2 = nw2, w3 = nw3;
            e += 4;
            if (e < end) {
                int i1 = (e + 1 <= en) ? e + 1 : en;
                int i2 = (e + 2 <= en) ? e + 2 : en;
                int i3 = (e + 3 <= en) ? e + 3 : en;
                int s0 = csr[e], s1 = csr[i1], s2 = csr[i2], s3 = csr[i3];
                nw0 = dis[s0];
                nw1 = (e + 1 <= en) ? dis[s1] : 0.f;
                nw2 = (e + 2 <= en) ? dis[s2] : 0.f;
                nw3 = (e + 3 <= en) ? dis[s3] : 0.f;
                nv0 = ((const half8*)(t + (size_t)s0 * DE))[lane];
                nv1 = ((const half8*)(t + (size_t)s1 * DE))[lane];
                nv2 = ((const half8*)(t + (size_t)s2 * DE))[lane];
                nv3 = ((const half8*)(t + (size_t)s3 * DE))[lane];
            }
            #pragma unroll
            for (int c = 0; c < 8; ++c) {
                a0[c] = fmaf((float)v0[c], w0, a0[c]);
                a1[c] = fmaf((float)v1[c], w1, a1[c]);
                a2[c] = fmaf((float)v2[c], w2, a2[c]);
                a3[c] = fmaf((float)v3[c], w3, a3[c]);
            }
        }
    }

    half8 sv = ((const half8*)(t + (size_t)node * DE))[lane];
    f32x4 bv0 = ((const f32x4*)bias)[lane * 2];
    f32x4 bv1 = ((const f32x4*)bias)[lane * 2 + 1];
    f32x4 o0, o1;
    bf16x8 hh, ll;
    #pragma unroll
    for (int c = 0; c < 8; ++c) {
        float b = (c < 4) ? bv0[c] : bv1[c - 4];
        float acc = (a0[c] + a1[c]) + (a2[c] + a3[c]);
        float o = fmaf(fmaf((float)sv[c], din, acc), din, b);
        if (c < 4) o0[c] = o; else o1[c - 4] = o;
        bf16_t h = (bf16_t)o;
        hh[c] = h;
        ll[c] = (bf16_t)(o - (float)h);
    }
    ((f32x4*)(out + (size_t)node * DE))[lane * 2]     = o0;
    ((f32x4*)(out + (size_t)node * DE))[lane * 2 + 1] = o1;
    *(bf16x8*)(Eh + (size_t)node * DE + lane * 8) = hh;
    *(bf16x8*)(El + (size_t)node * DE + lane * 8) = ll;
}

// ---------------- MFMA heads: emb[NNP,256] @ Wt[80,256] -> {oe,oh,og} ----------------
// 4 waves/block, each wave one 16-row tile x 5 col-tiles (16x16x32 MFMA, 3-term split).

__global__ __launch_bounds__(256) void k_heads_mfma(
    const bf16_t* __restrict__ Eh, const bf16_t* __restrict__ El,
    const bf16_t* __restrict__ Wth, const bf16_t* __restrict__ Wtl,
    const float* __restrict__ bc,
    float* __restrict__ oe, float* __restrict__ oh, float* __restrict__ og) {
    const int wave = threadIdx.x >> 6, lane = threadIdx.x & 63;
    const int quad = lane >> 4, l16 = lane & 15;
    const int row0 = blockIdx.x * 64 + wave * 16;

    f32x4 acc[5];
    #pragma unroll
    for (int j = 0; j < 5; ++j)
        #pragma unroll
        for (int r = 0; r < 4; ++r) acc[j][r] = 0.f;

    const size_t abase = (size_t)(row0 + l16) * 256 + quad * 8;
    #pragma unroll
    for (int ks = 0; ks < 256; ks += 32) {
        bf16x8 ah = *(const bf16x8*)(Eh + abase + ks);
        bf16x8 al = *(const bf16x8*)(El + abase + ks);
        #pragma unroll
        for (int j = 0; j < 5; ++j) {
            const size_t bbase = (size_t)(j * 16 + l16) * 256 + ks + quad * 8;
            bf16x8 bh = *(const bf16x8*)(Wth + bbase);
            bf16x8 bl = *(const bf16x8*)(Wtl + bbase);
            acc[j] = __builtin_amdgcn_mfma_f32_16x16x32_bf16(ah, bh, acc[j], 0, 0, 0);
            acc[j] = __builtin_amdgcn_mfma_f32_16x16x32_bf16(ah, bl, acc[j], 0, 0, 0);
            acc[j] = __builtin_amdgcn_mfma_f32_16x16x32_bf16(al, bh, acc[j], 0, 0, 0);
        }
    }

    #pragma unroll
    for (int j = 0; j < 5; ++j) {
        int col = j * 16 + l16;
        if (col < 72) {
            float b = bc[col];
            #pragma unroll
            for (int r = 0; r < 4; ++r) {
                int row = row0 + quad * 4 + r;
                if (row < NN) {
                    float v = acc[j][r] + b;
                    if (col < 7)       oe[(size_t)row * 7 + col] = v;
                    else if (col < 15) oh[(size_t)row * 8 + (col - 7)] = v;
                    else               og[(size_t)row * 57 + (col - 15)] = v;
                }
            }
        }
    }
}

// ---------------- launch ----------------

extern "C" void kernel_launch(void* const* d_in, const int* in_sizes, int n_in,
                              void* d_out, int out_size, void* d_ws, size_t ws_size,
                              hipStream_t stream) {
    const float* x   = (const float*)d_in[0];
    const int*   ei  = (const int*)d_in[1];
    const float* W1  = (const float*)d_in[2];
    const float* b1  = (const float*)d_in[3];
    const float* W2  = (const float*)d_in[4];
    const float* b2  = (const float*)d_in[5];
    const float* W3  = (const float*)d_in[6];
    const float* b3  = (const float*)d_in[7];
    const float* We  = (const float*)d_in[8];
    const float* be  = (const float*)d_in[9];
    const float* Wh  = (const float*)d_in[10];
    const float* bh  = (const float*)d_in[11];
    const float* Wg  = (const float*)d_in[12];
    const float* bg  = (const float*)d_in[13];

    const int* e_src = ei;
    const int* e_dst = ei + NE;

    // workspace layout (~210 MB)
    half_t* bufA = (half_t*)d_ws;                       // NNP*512 fp16 (GEMM out)
    bf16_t* Ah   = (bf16_t*)(bufA + (size_t)NNP * DH);  // NNP*512 bf16
    bf16_t* Al   = Ah + (size_t)NNP * DH;
    bf16_t* Bth  = Al + (size_t)NNP * DH;               // 512*512 bf16
    bf16_t* Btl  = Bth + (size_t)DH * DH;
    bf16_t* embh = Btl + (size_t)DH * DH;               // NNP*256 bf16
    bf16_t* embl = embh + (size_t)NNP * DE;
    bf16_t* Wth  = embl + (size_t)NNP * DE;             // 80*256 bf16
    bf16_t* Wtl  = Wth + 80 * 256;
    float*  bc   = (float*)(Wtl + 80 * 256);            // 80 fp32
    int*   indeg  = (int*)(bc + 128);
    int*   rowptr = indeg + 50048;                      // 50001 used
    int*   cursor = rowptr + 50048;
    float* dis    = (float*)(cursor + 50048);
    int*   csr    = (int*)(dis + 50048);                // 800000

    float* emb   = (float*)d_out;                       // 50000*256
    float* out_e = emb + (size_t)NN * DE;               // 50000*7
    float* out_h = out_e + (size_t)NN * 7;              // 50000*8
    float* out_g = out_h + (size_t)NN * 8;              // 50000*57

    // 1) CSR build
    k_zero_i32<<<(NN + 255) / 256, 256, 0, stream>>>(indeg, NN);
    k_indeg<<<(NE + 255) / 256, 256, 0, stream>>>(e_dst, indeg, NE);
    k_scan<<<1, 1024, 0, stream>>>(indeg, rowptr, cursor, dis, NN);
    k_fill<<<(NE + 255) / 256, 256, 0, stream>>>(e_src, e_dst, cursor, csr, NE);

    const int gy = NNP / 128;  // 391
    const long total4 = (long)NNP * DH / 4;

    // 2) layer 1
    k_split_pad<<<(int)((total4 + 255) / 256), 256, 0, stream>>>(x, Ah, Al, NN, DIN, total4);
    k_splitT<<<(DH * DH + 255) / 256, 256, 0, stream>>>(W1, Bth, Btl, DIN, DH);
    k_gemm_split<<<dim3(DH / 128, gy), 256, 0, stream>>>(Ah, Al, Bth, Btl, bufA, NN, DH, DIN);
    k_agg_split<<<NN / 2, 128, 0, stream>>>(bufA, rowptr, csr, dis, b1, Ah, Al);

    // 3) layer 2
    k_splitT<<<(DH * DH + 255) / 256, 256, 0, stream>>>(W2, Bth, Btl, DH, DH);
    k_gemm_split<<<dim3(DH / 128, gy), 256, 0, stream>>>(Ah, Al, Bth, Btl, bufA, NN, DH, DH);
    k_agg_split<<<NN / 2, 128, 0, stream>>>(bufA, rowptr, csr, dis, b2, Ah, Al);

    // 4) layer 3 -> emb (no relu) + bf16 split for heads
    k_splitT<<<(DH * DE + 255) / 256, 256, 0, stream>>>(W3, Bth, Btl, DH, DE);
    k_gemm_split<<<dim3(DE / 128, gy), 256, 0, stream>>>(Ah, Al, Bth, Btl, bufA, NN, DE, DH);
    k_agg_f32<<<NN / 4, 128, 0, stream>>>(bufA, rowptr, csr, dis, b3, emb, embh, embl);

    // 5) heads via MFMA
    k_headw<<<(80 * 256 + 255) / 256, 256, 0, stream>>>(We, be, Wh, bh, Wg, bg, Wth, Wtl, bc);
    k_heads_mfma<<<NNP / 64, 256, 0, stream>>>(embh, embl, Wth, Wtl, bc, out_e, out_h, out_g);
}